// Round 1
// baseline (354.853 us; speedup 1.0000x reference)
//
#include <hip/hip_runtime.h>
#include <stdint.h>

#define TOKENS 65536
#define CDIM 384
#define NEXP 5

typedef __attribute__((ext_vector_type(8))) short short8;
typedef __attribute__((ext_vector_type(4))) float floatx4;

__device__ inline unsigned short f2bf(float f) {
    union { float f; uint32_t u; } v; v.f = f;
    uint32_t r = v.u + 0x7fffu + ((v.u >> 16) & 1u);   // RNE for normal values
    return (unsigned short)(r >> 16);
}

// ---------------- Kernel 1: router (fp64 logits, top-2, softmax -> dense G[N][5]) ----
__global__ __launch_bounds__(256) void router_kernel(const float* __restrict__ x,
                                                     const float* __restrict__ Wg,
                                                     float* __restrict__ G) {
    int tok  = (blockIdx.x * 256 + threadIdx.x) >> 6;   // one wave per token
    int lane = threadIdx.x & 63;
    const float* xr = x + (size_t)tok * CDIM;
    double p[NEXP] = {0.0, 0.0, 0.0, 0.0, 0.0};
    #pragma unroll
    for (int it = 0; it < 6; ++it) {
        int c = it * 64 + lane;
        double v = (double)xr[c];                        // coalesced
        const float* wr = Wg + c * NEXP;                 // 7.7 KB, L1-hot
        #pragma unroll
        for (int e = 0; e < NEXP; ++e) p[e] += v * (double)wr[e];
    }
    #pragma unroll
    for (int off = 32; off > 0; off >>= 1) {
        #pragma unroll
        for (int e = 0; e < NEXP; ++e) p[e] += __shfl_down(p[e], off, 64);
    }
    if (lane == 0) {
        // top-2, ties -> lowest index (matches jax.lax.top_k)
        int i0 = 0;
        #pragma unroll
        for (int e = 1; e < NEXP; ++e) if (p[e] > p[i0]) i0 = e;
        int i1 = (i0 == 0) ? 1 : 0;
        #pragma unroll
        for (int e = 0; e < NEXP; ++e) if (e != i0 && p[e] > p[i1]) i1 = e;
        float d  = (float)(p[i1] - p[i0]);               // <= 0
        float e1 = expf(d);
        float s  = 1.0f + e1;
        float g0 = 1.0f / s, g1 = e1 / s;
        float* gr = G + (size_t)tok * NEXP;
        #pragma unroll
        for (int e = 0; e < NEXP; ++e) gr[e] = 0.0f;
        gr[i0] = g0;
        gr[i1] = g1;
    }
}

// ---------------- Kernel 2: We[e][c][d] fp32 -> WeT[e][d][c] bf16 (tiled transpose) --
__global__ __launch_bounds__(256) void convert_we(const float* __restrict__ We,
                                                  unsigned short* __restrict__ WeT) {
    __shared__ float tile[64][65];                       // +1 pad: no bank conflicts
    int e  = blockIdx.z;
    int c0 = blockIdx.x * 64, d0 = blockIdx.y * 64;
    int t  = threadIdx.x;
    const float* src = We + (size_t)e * CDIM * CDIM;
    int dr = t & 15, cr = t >> 4;
    for (int s = 0; s < 64; s += 16) {
        float4 v = *(const float4*)&src[(size_t)(c0 + cr + s) * CDIM + d0 + dr * 4];
        tile[cr + s][dr * 4 + 0] = v.x;
        tile[cr + s][dr * 4 + 1] = v.y;
        tile[cr + s][dr * 4 + 2] = v.z;
        tile[cr + s][dr * 4 + 3] = v.w;
    }
    __syncthreads();
    unsigned short* dst = WeT + (size_t)e * CDIM * CDIM;
    int c4 = t & 15, drow = t >> 4;
    for (int s = 0; s < 64; s += 16) {
        int d = drow + s;
        ushort4 o;
        o.x = f2bf(tile[c4 * 4 + 0][d]);
        o.y = f2bf(tile[c4 * 4 + 1][d]);
        o.z = f2bf(tile[c4 * 4 + 2][d]);
        o.w = f2bf(tile[c4 * 4 + 3][d]);
        *(ushort4*)&dst[(size_t)(d0 + d) * CDIM + c0 + c4 * 4] = o;
    }
}

// ---------------- Kernel 3: fused dense MoE GEMM + combine + bias + LeakyReLU -------
// tile: 128 tokens x 128 out-channels, K-loop BK=32, all 5 experts in-block.
__global__ __launch_bounds__(512, 2) void moe_kernel(const float* __restrict__ x,
                                                     const unsigned short* __restrict__ WeT,
                                                     const float* __restrict__ G,
                                                     const float* __restrict__ be,
                                                     float* __restrict__ out) {
    const int BM = 128, BK = 32;
    int bid = blockIdx.x;
    int nt = bid % 3, mt = bid / 3;                      // consecutive bids share mt (L2/L3 reuse of x rows)
    int m0 = mt * BM, n0 = nt * 128;
    int t = threadIdx.x;
    int lane = t & 63, wid = t >> 6;                     // 8 waves
    int wm = wid & 1, wn = wid >> 1;                     // wave tile: 64(m) x 32(n)
    __shared__ __align__(16) unsigned short As[BM * BK];          // [m][k]  8 KB
    __shared__ __align__(16) unsigned short Bs[NEXP][128 * BK];   // [n][k] per expert, 40 KB

    floatx4 acc[NEXP][4][2];
    #pragma unroll
    for (int e = 0; e < NEXP; ++e)
        #pragma unroll
        for (int i = 0; i < 4; ++i)
            #pragma unroll
            for (int j = 0; j < 2; ++j)
                acc[e][i][j] = (floatx4){0.0f, 0.0f, 0.0f, 0.0f};

    int srow = t >> 2, sp = t & 3;                       // staging: row 0..127, 16B piece 0..3
    const float*          xrow = x   + (size_t)(m0 + srow) * CDIM + sp * 8;
    const unsigned short* brow = WeT + (size_t)(n0 + srow) * CDIM + sp * 8;
    int q = lane >> 4, cc = lane & 15;

    for (int kc = 0; kc < 12; ++kc) {
        int k0 = kc * BK;
        __syncthreads();
        // stage A: 8 fp32 -> 8 bf16 per thread
        float4 a0 = *(const float4*)(xrow + k0);
        float4 a1 = *(const float4*)(xrow + k0 + 4);
        short8 av;
        av[0] = f2bf(a0.x); av[1] = f2bf(a0.y); av[2] = f2bf(a0.z); av[3] = f2bf(a0.w);
        av[4] = f2bf(a1.x); av[5] = f2bf(a1.y); av[6] = f2bf(a1.z); av[7] = f2bf(a1.w);
        *(short8*)&As[srow * BK + sp * 8] = av;
        // stage B for all 5 experts: 16B bf16 rows from hot L2
        #pragma unroll
        for (int e = 0; e < NEXP; ++e)
            *(short8*)&Bs[e][srow * BK + sp * 8] =
                *(const short8*)(brow + (size_t)e * CDIM * CDIM + k0);
        __syncthreads();

        short8 af[4];
        #pragma unroll
        for (int i = 0; i < 4; ++i)    // A[m=lane&15][k=q*8+j]
            af[i] = *(const short8*)&As[(wm * 64 + i * 16 + cc) * BK + q * 8];
        #pragma unroll
        for (int e = 0; e < NEXP; ++e) {
            short8 b0 = *(const short8*)&Bs[e][(wn * 32 + cc) * BK + q * 8];
            short8 b1 = *(const short8*)&Bs[e][(wn * 32 + 16 + cc) * BK + q * 8];
            #pragma unroll
            for (int i = 0; i < 4; ++i) {
                acc[e][i][0] = __builtin_amdgcn_mfma_f32_16x16x32_bf16(af[i], b0, acc[e][i][0], 0, 0, 0);
                acc[e][i][1] = __builtin_amdgcn_mfma_f32_16x16x32_bf16(af[i], b1, acc[e][i][1], 0, 0, 0);
            }
        }
    }

    // epilogue: y = leaky( sum_e g_e * (acc_e + be_e) )   [C/D: col=lane&15, row=q*4+r]
    #pragma unroll
    for (int i = 0; i < 4; ++i) {
        #pragma unroll
        for (int r = 0; r < 4; ++r) {
            int tok = m0 + wm * 64 + i * 16 + q * 4 + r;
            const float* g = G + (size_t)tok * NEXP;
            float g0 = g[0], g1 = g[1], g2 = g[2], g3 = g[3], g4 = g[4];
            #pragma unroll
            for (int j = 0; j < 2; ++j) {
                int oc = n0 + wn * 32 + j * 16 + cc;
                float v = g0 * acc[0][i][j][r] + g1 * acc[1][i][j][r] + g2 * acc[2][i][j][r]
                        + g3 * acc[3][i][j][r] + g4 * acc[4][i][j][r];
                v += g0 * be[0 * CDIM + oc] + g1 * be[1 * CDIM + oc] + g2 * be[2 * CDIM + oc]
                   + g3 * be[3 * CDIM + oc] + g4 * be[4 * CDIM + oc];
                v = v > 0.0f ? v : 0.01f * v;
                out[(size_t)tok * CDIM + oc] = v;
            }
        }
    }
}

extern "C" void kernel_launch(void* const* d_in, const int* in_sizes, int n_in,
                              void* d_out, int out_size, void* d_ws, size_t ws_size,
                              hipStream_t stream) {
    const float* x  = (const float*)d_in[0];
    const float* Wg = (const float*)d_in[1];
    const float* We = (const float*)d_in[2];
    const float* be = (const float*)d_in[3];
    float* out = (float*)d_out;

    float* G = (float*)d_ws;                                             // 65536*5 fp32 = 1.31 MB
    unsigned short* WeT =
        (unsigned short*)((char*)d_ws + (size_t)TOKENS * NEXP * sizeof(float)); // 5*384*384 bf16 = 1.47 MB

    router_kernel<<<TOKENS / 4, 256, 0, stream>>>(x, Wg, G);
    convert_we<<<dim3(6, 6, 5), 256, 0, stream>>>(We, WeT);
    moe_kernel<<<1536, 512, 0, stream>>>(x, WeT, G, be, out);
}